// Round 9
// baseline (502.624 us; speedup 1.0000x reference)
//
#include <hip/hip_runtime.h>
#include <hip/hip_bf16.h>

#define Sq 2048
#define Dm 2048
#define HDim 3072
#define QKVDim 9216
#define NH 24
#define DH 128
#define FF 8192
#define ATT_SCALE 0.08838834764831845f

using bf16 = __hip_bfloat16;
typedef __attribute__((ext_vector_type(8))) short bf16x8;
typedef __attribute__((ext_vector_type(4))) float f32x4;
typedef unsigned int u32;
typedef unsigned long long u64;
typedef __attribute__((ext_vector_type(4))) u32 u32x4;

// async global->LDS, 16B per lane; LDS dest = wave-uniform base + lane*16
__device__ __forceinline__ void gload_lds16(const void* g, void* l) {
    __builtin_amdgcn_global_load_lds(
        (const __attribute__((address_space(1))) void*)g,
        (__attribute__((address_space(3))) void*)l, 16, 0, 0);
}

// ---------------- LayerNorm + RMSNorm fused ----------------
__global__ __launch_bounds__(256) void ln_rms_kernel(
    const float* __restrict__ x, const float* __restrict__ g, const float* __restrict__ b,
    const float* __restrict__ ag, float* __restrict__ xnf, bf16* __restrict__ h)
{
    __shared__ float redA[4], redB[4], redC[4];
    int row = blockIdx.x;
    int t = threadIdx.x;
    int lane = t & 63, wid = t >> 6;
    const float* xr = x + (size_t)row * Dm;

    float v[8];
    float sum = 0.f, ssq = 0.f;
#pragma unroll
    for (int i = 0; i < 8; i++) {
        float f = xr[t + 256 * i];
        v[i] = f; sum += f; ssq += f * f;
    }
#pragma unroll
    for (int off = 32; off > 0; off >>= 1) {
        sum += __shfl_down(sum, off);
        ssq += __shfl_down(ssq, off);
    }
    if (lane == 0) { redA[wid] = sum; redB[wid] = ssq; }
    __syncthreads();
    sum = redA[0] + redA[1] + redA[2] + redA[3];
    ssq = redB[0] + redB[1] + redB[2] + redB[3];
    float mu = sum * (1.f / Dm);
    float var = ssq * (1.f / Dm) - mu * mu;
    float rstd = rsqrtf(var + 1e-5f);

    float xn[8];
    float s2 = 0.f;
#pragma unroll
    for (int i = 0; i < 8; i++) {
        int col = t + 256 * i;
        float xv = (v[i] - mu) * rstd * g[col] + b[col];
        xn[i] = xv;
        xnf[(size_t)row * Dm + col] = xv;
        s2 += xv * xv;
    }
#pragma unroll
    for (int off = 32; off > 0; off >>= 1) s2 += __shfl_down(s2, off);
    if (lane == 0) redC[wid] = s2;
    __syncthreads();
    s2 = redC[0] + redC[1] + redC[2] + redC[3];
    float rms = rsqrtf(s2 * (1.f / Dm) + 1e-5f);
#pragma unroll
    for (int i = 0; i < 8; i++) {
        int col = t + 256 * i;
        h[(size_t)row * Dm + col] = __float2bfloat16(xn[i] * rms * ag[col]);
    }
}

// ---------------- transpose + fp32->bf16 convert: W[K][N] -> Wt[N][K] ----------------
__global__ __launch_bounds__(256) void transpose_cvt_kernel(
    const float* __restrict__ W, bf16* __restrict__ Wt, int K, int N)
{
    __shared__ float tile[32][36];
    int n0 = blockIdx.x * 32, k0 = blockIdx.y * 32;
    int t = threadIdx.x;
    int r = t >> 3, c4 = (t & 7) * 4;
    f32x4 v = *reinterpret_cast<const f32x4*>(W + (size_t)(k0 + r) * N + n0 + c4);
    *reinterpret_cast<f32x4*>(&tile[r][c4]) = v;
    __syncthreads();
    int nr = t >> 3, kc = (t & 7) * 4;
    bf16 o4[4];
    o4[0] = __float2bfloat16(tile[kc + 0][nr]);
    o4[1] = __float2bfloat16(tile[kc + 1][nr]);
    o4[2] = __float2bfloat16(tile[kc + 2][nr]);
    o4[3] = __float2bfloat16(tile[kc + 3][nr]);
    *reinterpret_cast<u64*>(Wt + (size_t)(n0 + nr) * K + k0 + kc) = *reinterpret_cast<const u64*>(o4);
}

// 3-matrix variant for fused QKV weight transpose (z selects matrix)
__global__ __launch_bounds__(256) void transpose_cvt3_kernel(
    const float* __restrict__ Wa, const float* __restrict__ Wb, const float* __restrict__ Wc,
    bf16* __restrict__ Wt, int K, int N)
{
    __shared__ float tile[32][36];
    const float* W = blockIdx.z == 0 ? Wa : (blockIdx.z == 1 ? Wb : Wc);
    bf16* dst = Wt + (size_t)blockIdx.z * N * K;
    int n0 = blockIdx.x * 32, k0 = blockIdx.y * 32;
    int t = threadIdx.x;
    int r = t >> 3, c4 = (t & 7) * 4;
    f32x4 v = *reinterpret_cast<const f32x4*>(W + (size_t)(k0 + r) * N + n0 + c4);
    *reinterpret_cast<f32x4*>(&tile[r][c4]) = v;
    __syncthreads();
    int nr = t >> 3, kc = (t & 7) * 4;
    bf16 o4[4];
    o4[0] = __float2bfloat16(tile[kc + 0][nr]);
    o4[1] = __float2bfloat16(tile[kc + 1][nr]);
    o4[2] = __float2bfloat16(tile[kc + 2][nr]);
    o4[3] = __float2bfloat16(tile[kc + 3][nr]);
    *reinterpret_cast<u64*>(dst + (size_t)(n0 + nr) * K + k0 + kc) = *reinterpret_cast<const u64*>(o4);
}

// ---------------- fused: hb = bf16(xnf); out = xnf + b2 ----------------
__global__ __launch_bounds__(256) void cvt_prefill_kernel(
    const float* __restrict__ xnf, const float* __restrict__ bias,
    bf16* __restrict__ hb, float* __restrict__ o, int N)
{
    int i = (blockIdx.x * 256 + threadIdx.x) * 8;
    int col = i % N;
    f32x4 a = *reinterpret_cast<const f32x4*>(xnf + i);
    f32x4 b = *reinterpret_cast<const f32x4*>(xnf + i + 4);
    bf16 r[8];
#pragma unroll
    for (int j = 0; j < 4; j++) { r[j] = __float2bfloat16(a[j]); r[4 + j] = __float2bfloat16(b[j]); }
    *reinterpret_cast<u32x4*>(hb + i) = *reinterpret_cast<const u32x4*>(r);
    f32x4 b0 = *reinterpret_cast<const f32x4*>(bias + col);
    f32x4 b1v = *reinterpret_cast<const f32x4*>(bias + col + 4);
    f32x4 o0 = {a[0] + b0[0], a[1] + b0[1], a[2] + b0[2], a[3] + b0[3]};
    f32x4 o1 = {b[0] + b1v[0], b[1] + b1v[1], b[2] + b1v[2], b[3] + b1v[3]};
    *reinterpret_cast<f32x4*>(o + i) = o0;
    *reinterpret_cast<f32x4*>(o + i + 4) = o1;
}

// ---------------- 128x128 bf16 MFMA GEMM (m97 structure, BK=64, swizzled) ------
// EPI 0: Cb = bf16(acc);  EPI 2: Cb = bf16(gelu(acc+bias));  EPI 4: atomicAdd(Cf, acc)
template <int EPI>
__global__ __launch_bounds__(256, 4) void gemm_kernel(
    const bf16* __restrict__ A, const bf16* __restrict__ Bt,
    int M, int N, int K, int Ksplit,
    bf16* Cb, float* Cf, const float* __restrict__ bias)
{
    __shared__ __align__(16) bf16 As[128 * 64];
    __shared__ __align__(16) bf16 Bs[128 * 64];
    int m0 = blockIdx.y * 128, n0 = blockIdx.x * 128;
    int kbeg = blockIdx.z * Ksplit, kend = kbeg + Ksplit;
    int tid = threadIdx.x;
    int lane = tid & 63, w = tid >> 6;
    int wr = w >> 1, wc = w & 1;
    int l15 = lane & 15, lhi = lane >> 4;

    int srow = lane >> 3;
    int scol = ((lane & 7) ^ (lane >> 3)) * 8;

    const f32x4 zero4 = {0.f, 0.f, 0.f, 0.f};
    f32x4 acc[4][4];
#pragma unroll
    for (int m = 0; m < 4; m++)
#pragma unroll
        for (int n = 0; n < 4; n++) acc[m][n] = zero4;

    for (int k0 = kbeg; k0 < kend; k0 += 64) {
        __syncthreads();
#pragma unroll
        for (int c = 0; c < 4; c++) {
            int row = w * 32 + c * 8 + srow;
            gload_lds16(A + (size_t)(m0 + row) * K + k0 + scol,
                        (char*)As + w * 4096 + c * 1024);
            gload_lds16(Bt + (size_t)(n0 + row) * K + k0 + scol,
                        (char*)Bs + w * 4096 + c * 1024);
        }
        __syncthreads();
#pragma unroll
        for (int ks = 0; ks < 2; ks++) {
            bf16x8 af[4], bfr[4];
#pragma unroll
            for (int m = 0; m < 4; m++) {
                int r = wr * 64 + m * 16 + l15;
                af[m] = *reinterpret_cast<const bf16x8*>(
                    &As[r * 64 + (((ks << 2) + lhi) ^ (r & 7)) * 8]);
            }
#pragma unroll
            for (int n = 0; n < 4; n++) {
                int r = wc * 64 + n * 16 + l15;
                bfr[n] = *reinterpret_cast<const bf16x8*>(
                    &Bs[r * 64 + (((ks << 2) + lhi) ^ (r & 7)) * 8]);
            }
#pragma unroll
            for (int m = 0; m < 4; m++)
#pragma unroll
                for (int n = 0; n < 4; n++)
                    acc[m][n] = __builtin_amdgcn_mfma_f32_16x16x32_bf16(af[m], bfr[n], acc[m][n], 0, 0, 0);
        }
    }

#pragma unroll
    for (int m = 0; m < 4; m++) {
        int row = m0 + wr * 64 + m * 16 + lhi * 4;
#pragma unroll
        for (int n = 0; n < 4; n++) {
            int col = n0 + wc * 64 + n * 16 + l15;
#pragma unroll
            for (int j = 0; j < 4; j++) {
                float vv = acc[m][n][j];
                size_t idx = (size_t)(row + j) * N + col;
                if (EPI == 0) {
                    Cb[idx] = __float2bfloat16(vv);
                } else if (EPI == 2) {
                    float o = vv + bias[col];
                    float u = 1.5957691216057308f * (o + 0.044715f * o * o * o); // 2*sqrt(2/pi)
                    Cb[idx] = __float2bfloat16(o / (1.0f + __expf(-u)));
                } else {
                    atomicAdd(&Cf[idx], vv);
                }
            }
        }
    }
}

// ---------------- flash-style causal attention, QBLK=128, double-buffered K/V ---
// 1D grid NH*(Sq/128), work-descending. 4 waves; wave w owns q rows
// qb*128 + s*64 + w*16 (s=0,1).  Per kb: K(kb+1) gload_lds + V(kb+1)->regs issued
// BEFORE compute; V ds_write + vmcnt(0) after the compute barrier.
// V-write lane map kv = lhi*2+(w&1)+(w>>1)*8 makes the transpose writes
// conflict-free (bank = blk*4 + lhi, injective per 32-lane half).
__global__ __launch_bounds__(256) void attn_kernel(
    const bf16* __restrict__ qkv, bf16* __restrict__ o)
{
    __shared__ __align__(16) bf16 KsF[2][64 * 128];   // swizzled: slot s of row r = block s^(r&7)
    __shared__ __align__(16) bf16 VtF[2][128 * 72];   // V^T, kv-block XOR swizzle
    __shared__ __align__(16) bf16 Pl[4][16][72];      // per-wave P tile (reused per subtile)
    int rank = blockIdx.x;
    int qb = (Sq / 128 - 1) - rank / NH;   // heaviest first
    int head = rank % NH;
    const bf16* q = qkv + head * DH;
    const bf16* k = qkv + HDim + head * DH;
    const bf16* v = qkv + 2 * HDim + head * DH;
    int tid = threadIdx.x, lane = tid & 63, w = tid >> 6;
    int l15 = lane & 15, lhi = lane >> 4;

    bf16x8 aq[2][4];
#pragma unroll
    for (int s = 0; s < 2; s++) {
        const bf16* qbase = q + (size_t)(qb * 128 + s * 64 + w * 16 + l15) * QKVDim;
#pragma unroll
        for (int kk = 0; kk < 4; kk++)
            aq[s][kk] = *reinterpret_cast<const bf16x8*>(qbase + kk * 32 + lhi * 8);
    }

    int krow_st = w * 16;                   // + c*4 + lhi
    int vkv = lhi * 2 + (w & 1) + (w >> 1) * 8;   // conflict-free V write map
    int vd0 = l15 * 8;
    int vxr = l15 & 7;                      // (vd0>>3)&7, same for all 8 j

    const f32x4 zero4 = {0.f, 0.f, 0.f, 0.f};
    f32x4 acc_o[2][8];
    float mrow[2][4], lrow[2][4];
#pragma unroll
    for (int s = 0; s < 2; s++) {
#pragma unroll
        for (int db = 0; db < 8; db++) acc_o[s][db] = zero4;
#pragma unroll
        for (int r = 0; r < 4; r++) { mrow[s][r] = -1e30f; lrow[s][r] = 0.f; }
    }

    int nt = 2 * qb + 2;

    // prologue: stage tile 0 into buf 0
    {
#pragma unroll
        for (int c = 0; c < 4; c++) {
            int row = krow_st + c * 4 + lhi;
            int cb = l15 ^ (row & 7);
            gload_lds16(k + (size_t)row * QKVDim + cb * 8,
                        (char*)&KsF[0][0] + w * 4096 + c * 1024);
        }
#pragma unroll
        for (int i = 0; i < 4; i++) {
            int kv = vkv + i * 16;
            bf16x8 vv = *reinterpret_cast<const bf16x8*>(v + (size_t)kv * QKVDim + vd0);
            int vb = kv >> 3, kr = kv & 7;
#pragma unroll
            for (int j = 0; j < 8; j++)
                VtF[0][(vd0 + j) * 72 + ((vb ^ vxr) << 3) + kr] = ((const bf16*)&vv)[j];
        }
        asm volatile("s_waitcnt vmcnt(0)" ::: "memory");
        __syncthreads();
    }

    for (int kb = 0; kb < nt; kb++) {
        int kv0 = kb * 64;
        int p = kb & 1;
        bf16x8 vreg[4];
        bool pref = (kb + 1 < nt);
        if (pref) {
            int nv0 = kv0 + 64;
#pragma unroll
            for (int c = 0; c < 4; c++) {
                int row = krow_st + c * 4 + lhi;
                int cb = l15 ^ (row & 7);
                gload_lds16(k + (size_t)(nv0 + row) * QKVDim + cb * 8,
                            (char*)&KsF[p ^ 1][0] + w * 4096 + c * 1024);
            }
#pragma unroll
            for (int i = 0; i < 4; i++) {
                int kv = vkv + i * 16;
                vreg[i] = *reinterpret_cast<const bf16x8*>(v + (size_t)(nv0 + kv) * QKVDim + vd0);
            }
        }

        // ---- compute both q-subtiles on buf p ----
#pragma unroll
        for (int s = 0; s < 2; s++) {
            int qr0s = qb * 128 + s * 64 + w * 16;
            if (kv0 > qr0s + 15) continue;     // wave-uniform causal skip

            f32x4 sacc[4];
#pragma unroll
            for (int nb = 0; nb < 4; nb++) {
                sacc[nb] = zero4;
                int krow = nb * 16 + l15;
#pragma unroll
                for (int kk = 0; kk < 4; kk++) {
                    const char* kp = (const char*)&KsF[p][0] + krow * 256 +
                                     ((kk * 64 + lhi * 16) ^ ((krow & 7) << 4));
                    bf16x8 bk = *reinterpret_cast<const bf16x8*>(kp);
                    sacc[nb] = __builtin_amdgcn_mfma_f32_16x16x32_bf16(aq[s][kk], bk, sacc[nb], 0, 0, 0);
                }
            }

            bool msk = (kv0 + 63 > qr0s);
            float sv[4][4];
            float pm[4];
#pragma unroll
            for (int r = 0; r < 4; r++) pm[r] = -1e30f;
#pragma unroll
            for (int nb = 0; nb < 4; nb++) {
                int kvc = kv0 + nb * 16 + l15;
#pragma unroll
                for (int r = 0; r < 4; r++) {
                    int qr = qr0s + lhi * 4 + r;
                    float ss = sacc[nb][r] * ATT_SCALE;
                    if (msk && kvc > qr) ss = -1e30f;
                    sv[nb][r] = ss;
                    pm[r] = fmaxf(pm[r], ss);
                }
            }
#pragma unroll
            for (int off = 1; off < 16; off <<= 1)
#pragma unroll
                for (int r = 0; r < 4; r++)
                    pm[r] = fmaxf(pm[r], __shfl_xor(pm[r], off));

            float ls[4];
#pragma unroll
            for (int r = 0; r < 4; r++) {
                float mnew = fmaxf(mrow[s][r], pm[r]);
                float sc = __expf(mrow[s][r] - mnew);
                mrow[s][r] = mnew;
                lrow[s][r] *= sc;
#pragma unroll
                for (int db = 0; db < 8; db++) acc_o[s][db][r] *= sc;
                float lsr = 0.f;
#pragma unroll
                for (int nb = 0; nb < 4; nb++) {
                    float pp = __expf(sv[nb][r] - mnew);
                    sv[nb][r] = pp;
                    lsr += pp;
                }
                ls[r] = lsr;
            }
#pragma unroll
            for (int off = 1; off < 16; off <<= 1)
#pragma unroll
                for (int r = 0; r < 4; r++)
                    ls[r] += __shfl_xor(ls[r], off);
#pragma unroll
            for (int r = 0; r < 4; r++) lrow[s][r] += ls[r];

#pragma unroll
            for (int nb = 0; nb < 4; nb++)
#pragma unroll
                for (int r = 0; r < 4; r++)
                    Pl[w][lhi * 4 + r][nb * 16 + l15] = __float2bfloat16(sv[nb][r]);

#pragma unroll
            for (int ks = 0; ks < 2; ks++) {
                bf16x8 ap = *reinterpret_cast<const bf16x8*>(&Pl[w][l15][ks * 32 + lhi * 8]);
#pragma unroll
                for (int db = 0; db < 8; db++) {
                    int dv = db * 16 + l15;
                    int blk = (ks * 4 + lhi) ^ ((dv >> 3) & 7);
                    bf16x8 bv = *reinterpret_cast<const bf16x8*>(&VtF[p][dv * 72 + blk * 8]);
                    acc_o[s][db] = __builtin_amdgcn_mfma_f32_16x16x32_bf16(ap, bv, acc_o[s][db], 0, 0, 0);
                }
            }
        }

        __syncthreads();                      // all waves done reading buf p
        if (pref) {
            int nv0 = kv0 + 64;
            (void)nv0;
#pragma unroll
            for (int i = 0; i < 4; i++) {
                int kv = vkv + i * 16;
                int vb = kv >> 3, kr = kv & 7;
#pragma unroll
                for (int j = 0; j < 8; j++)
                    VtF[p ^ 1][(vd0 + j) * 72 + ((vb ^ vxr) << 3) + kr] = ((const bf16*)&vreg[i])[j];
            }
            asm volatile("s_waitcnt vmcnt(0)" ::: "memory");
            __syncthreads();                  // buf p^1 ready
        }
    }

#pragma unroll
    for (int s = 0; s < 2; s++)
#pragma unroll
        for (int db = 0; db < 8; db++)
#pragma unroll
            for (int r = 0; r < 4; r++) {
                int qr = qb * 128 + s * 64 + w * 16 + lhi * 4 + r;
                float val = acc_o[s][db][r] / lrow[s][r];
                o[(size_t)qr * HDim + head * DH + db * 16 + l15] = __float2bfloat16(val);
            }
}

// ---------------- host launch ----------------
extern "C" void kernel_launch(void* const* d_in, const int* in_sizes, int n_in,
                              void* d_out, int out_size, void* d_ws, size_t ws_size,
                              hipStream_t stream)
{
    const float* x     = (const float*)d_in[0];
    const float* ln_g  = (const float*)d_in[1];
    const float* ln_b  = (const float*)d_in[2];
    const float* attng = (const float*)d_in[3];
    const float* Wq    = (const float*)d_in[4];
    const float* Wk    = (const float*)d_in[5];
    const float* Wv    = (const float*)d_in[6];
    const float* Wo    = (const float*)d_in[7];
    const float* W1    = (const float*)d_in[8];
    const float* b1    = (const float*)d_in[9];
    const float* W2    = (const float*)d_in[10];
    const float* b2    = (const float*)d_in[11];
    float* out = (float*)d_out;
    char* ws = (char*)d_ws;

    bf16*  wbuf = (bf16*)(ws + 0);           // 38 MB: transposed weights
    float* xnf  = (float*)(ws + 39845888);   // 16 MB: LN out fp32 -> x2 after Wo accum
    bf16*  hbuf = (bf16*)(ws + 56623104);    //  8 MB: rmsnorm bf16 -> x2 bf16
    bf16*  qkv  = (bf16*)(ws + 65011712);    // 36 MB: fused q|k|v; later FFN hidden
    bf16*  ob_  = (bf16*)(ws + 102760448);   // 12 MB: attention out
    bf16*  gb_  = qkv;

    ln_rms_kernel<<<Sq, 256, 0, stream>>>(x, ln_g, ln_b, attng, xnf, hbuf);

    transpose_cvt3_kernel<<<dim3(HDim / 32, Dm / 32, 3), 256, 0, stream>>>(
        Wq, Wk, Wv, wbuf, Dm, HDim);
    gemm_kernel<0><<<dim3(QKVDim / 128, Sq / 128, 1), 256, 0, stream>>>(
        hbuf, wbuf, Sq, QKVDim, Dm, Dm, qkv, nullptr, nullptr);

    attn_kernel<<<dim3(NH * Sq / 128), 256, 0, stream>>>(qkv, ob_);

    transpose_cvt_kernel<<<dim3(Dm / 32, HDim / 32), 256, 0, stream>>>(Wo, wbuf, HDim, Dm);
    gemm_kernel<4><<<dim3(Dm / 128, Sq / 128, 2), 256, 0, stream>>>(
        ob_, wbuf, Sq, Dm, HDim, HDim / 2, nullptr, xnf, nullptr);
    cvt_prefill_kernel<<<(Sq * Dm) / (256 * 8), 256, 0, stream>>>(xnf, b2, hbuf, out, Dm);

    transpose_cvt_kernel<<<dim3(FF / 32, Dm / 32), 256, 0, stream>>>(W1, wbuf, Dm, FF);
    gemm_kernel<2><<<dim3(FF / 128, Sq / 128, 1), 256, 0, stream>>>(
        hbuf, wbuf, Sq, FF, Dm, Dm, gb_, nullptr, b1);

    transpose_cvt_kernel<<<dim3(Dm / 32, FF / 32), 256, 0, stream>>>(W2, wbuf, FF, Dm);
    gemm_kernel<4><<<dim3(Dm / 128, Sq / 128, 2), 256, 0, stream>>>(
        gb_, wbuf, Sq, Dm, FF, FF / 2, nullptr, out, nullptr);
}

// Round 10
// 493.319 us; speedup vs baseline: 1.0189x; 1.0189x over previous
//
#include <hip/hip_runtime.h>
#include <hip/hip_bf16.h>

#define Sq 2048
#define Dm 2048
#define HDim 3072
#define QKVDim 9216
#define NH 24
#define DH 128
#define FF 8192
#define ATT_SCALE 0.08838834764831845f

using bf16 = __hip_bfloat16;
typedef __attribute__((ext_vector_type(8))) short bf16x8;
typedef __attribute__((ext_vector_type(4))) float f32x4;
typedef unsigned int u32;
typedef unsigned long long u64;
typedef __attribute__((ext_vector_type(4))) u32 u32x4;

// async global->LDS, 16B per lane; LDS dest = wave-uniform base + lane*16
__device__ __forceinline__ void gload_lds16(const void* g, void* l) {
    __builtin_amdgcn_global_load_lds(
        (const __attribute__((address_space(1))) void*)g,
        (__attribute__((address_space(3))) void*)l, 16, 0, 0);
}

// ---------------- LayerNorm + RMSNorm fused ----------------
__global__ __launch_bounds__(256) void ln_rms_kernel(
    const float* __restrict__ x, const float* __restrict__ g, const float* __restrict__ b,
    const float* __restrict__ ag, float* __restrict__ xnf, bf16* __restrict__ h)
{
    __shared__ float redA[4], redB[4], redC[4];
    int row = blockIdx.x;
    int t = threadIdx.x;
    int lane = t & 63, wid = t >> 6;
    const float* xr = x + (size_t)row * Dm;

    float v[8];
    float sum = 0.f, ssq = 0.f;
#pragma unroll
    for (int i = 0; i < 8; i++) {
        float f = xr[t + 256 * i];
        v[i] = f; sum += f; ssq += f * f;
    }
#pragma unroll
    for (int off = 32; off > 0; off >>= 1) {
        sum += __shfl_down(sum, off);
        ssq += __shfl_down(ssq, off);
    }
    if (lane == 0) { redA[wid] = sum; redB[wid] = ssq; }
    __syncthreads();
    sum = redA[0] + redA[1] + redA[2] + redA[3];
    ssq = redB[0] + redB[1] + redB[2] + redB[3];
    float mu = sum * (1.f / Dm);
    float var = ssq * (1.f / Dm) - mu * mu;
    float rstd = rsqrtf(var + 1e-5f);

    float xn[8];
    float s2 = 0.f;
#pragma unroll
    for (int i = 0; i < 8; i++) {
        int col = t + 256 * i;
        float xv = (v[i] - mu) * rstd * g[col] + b[col];
        xn[i] = xv;
        xnf[(size_t)row * Dm + col] = xv;
        s2 += xv * xv;
    }
#pragma unroll
    for (int off = 32; off > 0; off >>= 1) s2 += __shfl_down(s2, off);
    if (lane == 0) redC[wid] = s2;
    __syncthreads();
    s2 = redC[0] + redC[1] + redC[2] + redC[3];
    float rms = rsqrtf(s2 * (1.f / Dm) + 1e-5f);
#pragma unroll
    for (int i = 0; i < 8; i++) {
        int col = t + 256 * i;
        h[(size_t)row * Dm + col] = __float2bfloat16(xn[i] * rms * ag[col]);
    }
}

// ---------------- transpose + fp32->bf16 convert: W[K][N] -> Wt[N][K] ----------------
__global__ __launch_bounds__(256) void transpose_cvt_kernel(
    const float* __restrict__ W, bf16* __restrict__ Wt, int K, int N)
{
    __shared__ float tile[32][36];
    int n0 = blockIdx.x * 32, k0 = blockIdx.y * 32;
    int t = threadIdx.x;
    int r = t >> 3, c4 = (t & 7) * 4;
    f32x4 v = *reinterpret_cast<const f32x4*>(W + (size_t)(k0 + r) * N + n0 + c4);
    *reinterpret_cast<f32x4*>(&tile[r][c4]) = v;
    __syncthreads();
    int nr = t >> 3, kc = (t & 7) * 4;
    bf16 o4[4];
    o4[0] = __float2bfloat16(tile[kc + 0][nr]);
    o4[1] = __float2bfloat16(tile[kc + 1][nr]);
    o4[2] = __float2bfloat16(tile[kc + 2][nr]);
    o4[3] = __float2bfloat16(tile[kc + 3][nr]);
    *reinterpret_cast<u64*>(Wt + (size_t)(n0 + nr) * K + k0 + kc) = *reinterpret_cast<const u64*>(o4);
}

// 3-matrix variant for fused QKV weight transpose (z selects matrix)
__global__ __launch_bounds__(256) void transpose_cvt3_kernel(
    const float* __restrict__ Wa, const float* __restrict__ Wb, const float* __restrict__ Wc,
    bf16* __restrict__ Wt, int K, int N)
{
    __shared__ float tile[32][36];
    const float* W = blockIdx.z == 0 ? Wa : (blockIdx.z == 1 ? Wb : Wc);
    bf16* dst = Wt + (size_t)blockIdx.z * N * K;
    int n0 = blockIdx.x * 32, k0 = blockIdx.y * 32;
    int t = threadIdx.x;
    int r = t >> 3, c4 = (t & 7) * 4;
    f32x4 v = *reinterpret_cast<const f32x4*>(W + (size_t)(k0 + r) * N + n0 + c4);
    *reinterpret_cast<f32x4*>(&tile[r][c4]) = v;
    __syncthreads();
    int nr = t >> 3, kc = (t & 7) * 4;
    bf16 o4[4];
    o4[0] = __float2bfloat16(tile[kc + 0][nr]);
    o4[1] = __float2bfloat16(tile[kc + 1][nr]);
    o4[2] = __float2bfloat16(tile[kc + 2][nr]);
    o4[3] = __float2bfloat16(tile[kc + 3][nr]);
    *reinterpret_cast<u64*>(dst + (size_t)(n0 + nr) * K + k0 + kc) = *reinterpret_cast<const u64*>(o4);
}

// ---------------- fused: hb = bf16(xnf); out = xnf + b2 ----------------
__global__ __launch_bounds__(256) void cvt_prefill_kernel(
    const float* __restrict__ xnf, const float* __restrict__ bias,
    bf16* __restrict__ hb, float* __restrict__ o, int N)
{
    int i = (blockIdx.x * 256 + threadIdx.x) * 8;
    int col = i % N;
    f32x4 a = *reinterpret_cast<const f32x4*>(xnf + i);
    f32x4 b = *reinterpret_cast<const f32x4*>(xnf + i + 4);
    bf16 r[8];
#pragma unroll
    for (int j = 0; j < 4; j++) { r[j] = __float2bfloat16(a[j]); r[4 + j] = __float2bfloat16(b[j]); }
    *reinterpret_cast<u32x4*>(hb + i) = *reinterpret_cast<const u32x4*>(r);
    f32x4 b0 = *reinterpret_cast<const f32x4*>(bias + col);
    f32x4 b1v = *reinterpret_cast<const f32x4*>(bias + col + 4);
    f32x4 o0 = {a[0] + b0[0], a[1] + b0[1], a[2] + b0[2], a[3] + b0[3]};
    f32x4 o1 = {b[0] + b1v[0], b[1] + b1v[1], b[2] + b1v[2], b[3] + b1v[3]};
    *reinterpret_cast<f32x4*>(o + i) = o0;
    *reinterpret_cast<f32x4*>(o + i + 4) = o1;
}

// ---------------- 128x128 bf16 MFMA GEMM (m97 structure, BK=64, swizzled) ------
// EPI 0: Cb = bf16(acc);  EPI 2: Cb = bf16(gelu(acc+bias));  EPI 4: atomicAdd(Cf, acc)
template <int EPI>
__global__ __launch_bounds__(256, 4) void gemm_kernel(
    const bf16* __restrict__ A, const bf16* __restrict__ Bt,
    int M, int N, int K, int Ksplit,
    bf16* Cb, float* Cf, const float* __restrict__ bias)
{
    __shared__ __align__(16) bf16 As[128 * 64];
    __shared__ __align__(16) bf16 Bs[128 * 64];
    int m0 = blockIdx.y * 128, n0 = blockIdx.x * 128;
    int kbeg = blockIdx.z * Ksplit, kend = kbeg + Ksplit;
    int tid = threadIdx.x;
    int lane = tid & 63, w = tid >> 6;
    int wr = w >> 1, wc = w & 1;
    int l15 = lane & 15, lhi = lane >> 4;

    int srow = lane >> 3;
    int scol = ((lane & 7) ^ (lane >> 3)) * 8;

    const f32x4 zero4 = {0.f, 0.f, 0.f, 0.f};
    f32x4 acc[4][4];
#pragma unroll
    for (int m = 0; m < 4; m++)
#pragma unroll
        for (int n = 0; n < 4; n++) acc[m][n] = zero4;

    for (int k0 = kbeg; k0 < kend; k0 += 64) {
        __syncthreads();
#pragma unroll
        for (int c = 0; c < 4; c++) {
            int row = w * 32 + c * 8 + srow;
            gload_lds16(A + (size_t)(m0 + row) * K + k0 + scol,
                        (char*)As + w * 4096 + c * 1024);
            gload_lds16(Bt + (size_t)(n0 + row) * K + k0 + scol,
                        (char*)Bs + w * 4096 + c * 1024);
        }
        __syncthreads();
#pragma unroll
        for (int ks = 0; ks < 2; ks++) {
            bf16x8 af[4], bfr[4];
#pragma unroll
            for (int m = 0; m < 4; m++) {
                int r = wr * 64 + m * 16 + l15;
                af[m] = *reinterpret_cast<const bf16x8*>(
                    &As[r * 64 + (((ks << 2) + lhi) ^ (r & 7)) * 8]);
            }
#pragma unroll
            for (int n = 0; n < 4; n++) {
                int r = wc * 64 + n * 16 + l15;
                bfr[n] = *reinterpret_cast<const bf16x8*>(
                    &Bs[r * 64 + (((ks << 2) + lhi) ^ (r & 7)) * 8]);
            }
#pragma unroll
            for (int m = 0; m < 4; m++)
#pragma unroll
                for (int n = 0; n < 4; n++)
                    acc[m][n] = __builtin_amdgcn_mfma_f32_16x16x32_bf16(af[m], bfr[n], acc[m][n], 0, 0, 0);
        }
    }

#pragma unroll
    for (int m = 0; m < 4; m++) {
        int row = m0 + wr * 64 + m * 16 + lhi * 4;
#pragma unroll
        for (int n = 0; n < 4; n++) {
            int col = n0 + wc * 64 + n * 16 + l15;
#pragma unroll
            for (int j = 0; j < 4; j++) {
                float vv = acc[m][n][j];
                size_t idx = (size_t)(row + j) * N + col;
                if (EPI == 0) {
                    Cb[idx] = __float2bfloat16(vv);
                } else if (EPI == 2) {
                    float o = vv + bias[col];
                    float u = 1.5957691216057308f * (o + 0.044715f * o * o * o); // 2*sqrt(2/pi)
                    Cb[idx] = __float2bfloat16(o / (1.0f + __expf(-u)));
                } else {
                    atomicAdd(&Cf[idx], vv);
                }
            }
        }
    }
}

// ---------------- flash-style causal attention, K in registers ----------------
// 1D grid NH*(Sq/64), work-descending. QBLK=64 (4 waves x 16 q-rows).
// K B-fragments load straight from global (L2-resident) into bk[4][4];
// prefetch for kb+1 issued right after QK(kb) consumes bk (single reg set,
// latency hidden under softmax+PV). No K LDS, no manual vmcnt.
// V double-buffered in LDS (transposed, swizzled), reg-prefetch + write-late;
// V-write lane map kv=lhi*2+(w&1)+(w>>1)*8, d0=l15*8 -> exact 2-way banks (free).
__global__ __launch_bounds__(256) void attn_kernel(
    const bf16* __restrict__ qkv, bf16* __restrict__ o)
{
    __shared__ __align__(16) bf16 VtF[2][128 * 72];   // V^T, kv-block XOR swizzle
    __shared__ __align__(16) bf16 Pl[4][16][72];
    int rank = blockIdx.x;
    int qb = (Sq / 64 - 1) - rank / NH;    // heaviest first
    int head = rank % NH;
    const bf16* q = qkv + head * DH;
    const bf16* k = qkv + HDim + head * DH;
    const bf16* v = qkv + 2 * HDim + head * DH;
    int tid = threadIdx.x, lane = tid & 63, w = tid >> 6;
    int l15 = lane & 15, lhi = lane >> 4;
    int qrow0 = qb * 64 + w * 16;

    bf16x8 aq[4];
    const bf16* qbase = q + (size_t)(qrow0 + l15) * QKVDim;
#pragma unroll
    for (int kk = 0; kk < 4; kk++)
        aq[kk] = *reinterpret_cast<const bf16x8*>(qbase + kk * 32 + lhi * 8);

    // per-lane K fragment base: row l15 (+nb*16), col lhi*8 (+kk*32)
    const bf16* kbase = k + (size_t)l15 * QKVDim + lhi * 8;

    int vkv = lhi * 2 + (w & 1) + (w >> 1) * 8;   // conflict-free V write map
    int vd0 = l15 * 8;
    int vxr = l15 & 7;
    const bf16* vbase = v + (size_t)vkv * QKVDim + vd0;

    const f32x4 zero4 = {0.f, 0.f, 0.f, 0.f};
    f32x4 acc_o[8];
#pragma unroll
    for (int db = 0; db < 8; db++) acc_o[db] = zero4;
    float mrow[4], lrow[4];
#pragma unroll
    for (int r = 0; r < 4; r++) { mrow[r] = -1e30f; lrow[r] = 0.f; }

    int nt = qb + 1;
    bf16x8 bk[4][4], vreg[4];

    // prologue: K(0) frags + V(0) regs; V -> VtF[0]
#pragma unroll
    for (int nb = 0; nb < 4; nb++)
#pragma unroll
        for (int kk = 0; kk < 4; kk++)
            bk[nb][kk] = *reinterpret_cast<const bf16x8*>(
                kbase + (size_t)(nb * 16) * QKVDim + kk * 32);
#pragma unroll
    for (int i = 0; i < 4; i++)
        vreg[i] = *reinterpret_cast<const bf16x8*>(vbase + (size_t)(i * 16) * QKVDim);
#pragma unroll
    for (int i = 0; i < 4; i++) {
        int kv = vkv + i * 16, vb = kv >> 3, kr = kv & 7;
#pragma unroll
        for (int j = 0; j < 8; j++)
            VtF[0][(vd0 + j) * 72 + ((vb ^ vxr) << 3) + kr] = ((const bf16*)&vreg[i])[j];
    }
    __syncthreads();

    for (int kb = 0; kb < nt; kb++) {
        int kv0 = kb * 64, p = kb & 1;
        bool pref = (kb + 1 < nt);
        size_t nref = (size_t)(kv0 + 64) * QKVDim;
        if (pref) {
#pragma unroll
            for (int i = 0; i < 4; i++)
                vreg[i] = *reinterpret_cast<const bf16x8*>(
                    vbase + nref + (size_t)(i * 16) * QKVDim);
        }

        // S = Q K^T (bk registers)
        f32x4 sacc[4];
#pragma unroll
        for (int nb = 0; nb < 4; nb++) {
            sacc[nb] = zero4;
#pragma unroll
            for (int kk = 0; kk < 4; kk++)
                sacc[nb] = __builtin_amdgcn_mfma_f32_16x16x32_bf16(aq[kk], bk[nb][kk], sacc[nb], 0, 0, 0);
        }

        // prefetch K(kb+1) into bk (WAR after QK reads; hides under softmax+PV)
        if (pref) {
#pragma unroll
            for (int nb = 0; nb < 4; nb++)
#pragma unroll
                for (int kk = 0; kk < 4; kk++)
                    bk[nb][kk] = *reinterpret_cast<const bf16x8*>(
                        kbase + nref + (size_t)(nb * 16) * QKVDim + kk * 32);
        }

        bool diag = (kb == qb);
        float sv[4][4];
        float pm[4];
#pragma unroll
        for (int r = 0; r < 4; r++) pm[r] = -1e30f;
#pragma unroll
        for (int nb = 0; nb < 4; nb++) {
            int kvc = kv0 + nb * 16 + l15;
#pragma unroll
            for (int r = 0; r < 4; r++) {
                int qr = qrow0 + lhi * 4 + r;
                float s = sacc[nb][r] * ATT_SCALE;
                if (diag && kvc > qr) s = -1e30f;
                sv[nb][r] = s;
                pm[r] = fmaxf(pm[r], s);
            }
        }
#pragma unroll
        for (int off = 1; off < 16; off <<= 1)
#pragma unroll
            for (int r = 0; r < 4; r++)
                pm[r] = fmaxf(pm[r], __shfl_xor(pm[r], off));

        float ls[4];
#pragma unroll
        for (int r = 0; r < 4; r++) {
            float mnew = fmaxf(mrow[r], pm[r]);
            float sc = __expf(mrow[r] - mnew);
            mrow[r] = mnew;
            lrow[r] *= sc;
#pragma unroll
            for (int db = 0; db < 8; db++) acc_o[db][r] *= sc;
            float lsr = 0.f;
#pragma unroll
            for (int nb = 0; nb < 4; nb++) {
                float pp = __expf(sv[nb][r] - mnew);
                sv[nb][r] = pp;
                lsr += pp;
            }
            ls[r] = lsr;
        }
#pragma unroll
        for (int off = 1; off < 16; off <<= 1)
#pragma unroll
            for (int r = 0; r < 4; r++)
                ls[r] += __shfl_xor(ls[r], off);
#pragma unroll
        for (int r = 0; r < 4; r++) lrow[r] += ls[r];

        // P -> LDS (per-wave tile; same-wave read, lgkm tracked by compiler)
#pragma unroll
        for (int nb = 0; nb < 4; nb++)
#pragma unroll
            for (int r = 0; r < 4; r++)
                Pl[w][lhi * 4 + r][nb * 16 + l15] = __float2bfloat16(sv[nb][r]);

        // O += P V
#pragma unroll
        for (int ks = 0; ks < 2; ks++) {
            bf16x8 ap = *reinterpret_cast<const bf16x8*>(&Pl[w][l15][ks * 32 + lhi * 8]);
#pragma unroll
            for (int db = 0; db < 8; db++) {
                int dv = db * 16 + l15;
                int blk = (ks * 4 + lhi) ^ ((dv >> 3) & 7);
                bf16x8 bv = *reinterpret_cast<const bf16x8*>(&VtF[p][dv * 72 + blk * 8]);
                acc_o[db] = __builtin_amdgcn_mfma_f32_16x16x32_bf16(ap, bv, acc_o[db], 0, 0, 0);
            }
        }

        __syncthreads();                      // all waves done reading VtF[p]
        if (pref) {
#pragma unroll
            for (int i = 0; i < 4; i++) {
                int kv = vkv + i * 16, vb = kv >> 3, kr = kv & 7;
#pragma unroll
                for (int j = 0; j < 8; j++)
                    VtF[p ^ 1][(vd0 + j) * 72 + ((vb ^ vxr) << 3) + kr] = ((const bf16*)&vreg[i])[j];
            }
            __syncthreads();                  // VtF[p^1] ready
        }
    }

#pragma unroll
    for (int db = 0; db < 8; db++)
#pragma unroll
        for (int r = 0; r < 4; r++) {
            int qr = qrow0 + lhi * 4 + r;
            float val = acc_o[db][r] / lrow[r];
            o[(size_t)qr * HDim + head * DH + db * 16 + l15] = __float2bfloat16(val);
        }
}

// ---------------- host launch ----------------
extern "C" void kernel_launch(void* const* d_in, const int* in_sizes, int n_in,
                              void* d_out, int out_size, void* d_ws, size_t ws_size,
                              hipStream_t stream)
{
    const float* x     = (const float*)d_in[0];
    const float* ln_g  = (const float*)d_in[1];
    const float* ln_b  = (const float*)d_in[2];
    const float* attng = (const float*)d_in[3];
    const float* Wq    = (const float*)d_in[4];
    const float* Wk    = (const float*)d_in[5];
    const float* Wv    = (const float*)d_in[6];
    const float* Wo    = (const float*)d_in[7];
    const float* W1    = (const float*)d_in[8];
    const float* b1    = (const float*)d_in[9];
    const float* W2    = (const float*)d_in[10];
    const float* b2    = (const float*)d_in[11];
    float* out = (float*)d_out;
    char* ws = (char*)d_ws;

    bf16*  wbuf = (bf16*)(ws + 0);           // 38 MB: transposed weights
    float* xnf  = (float*)(ws + 39845888);   // 16 MB: LN out fp32 -> x2 after Wo accum
    bf16*  hbuf = (bf16*)(ws + 56623104);    //  8 MB: rmsnorm bf16 -> x2 bf16
    bf16*  qkv  = (bf16*)(ws + 65011712);    // 36 MB: fused q|k|v; later FFN hidden
    bf16*  ob_  = (bf16*)(ws + 102760448);   // 12 MB: attention out
    bf16*  gb_  = qkv;

    ln_rms_kernel<<<Sq, 256, 0, stream>>>(x, ln_g, ln_b, attng, xnf, hbuf);

    transpose_cvt3_kernel<<<dim3(HDim / 32, Dm / 32, 3), 256, 0, stream>>>(
        Wq, Wk, Wv, wbuf, Dm, HDim);
    gemm_kernel<0><<<dim3(QKVDim / 128, Sq / 128, 1), 256, 0, stream>>>(
        hbuf, wbuf, Sq, QKVDim, Dm, Dm, qkv, nullptr, nullptr);

    attn_kernel<<<dim3(NH * Sq / 64), 256, 0, stream>>>(qkv, ob_);

    transpose_cvt_kernel<<<dim3(Dm / 32, HDim / 32), 256, 0, stream>>>(Wo, wbuf, HDim, Dm);
    gemm_kernel<4><<<dim3(Dm / 128, Sq / 128, 2), 256, 0, stream>>>(
        ob_, wbuf, Sq, Dm, HDim, HDim / 2, nullptr, xnf, nullptr);
    cvt_prefill_kernel<<<(Sq * Dm) / (256 * 8), 256, 0, stream>>>(xnf, b2, hbuf, out, Dm);

    transpose_cvt_kernel<<<dim3(FF / 32, Dm / 32), 256, 0, stream>>>(W1, wbuf, Dm, FF);
    gemm_kernel<2><<<dim3(FF / 128, Sq / 128, 1), 256, 0, stream>>>(
        hbuf, wbuf, Sq, FF, Dm, Dm, gb_, nullptr, b1);

    transpose_cvt_kernel<<<dim3(Dm / 32, FF / 32), 256, 0, stream>>>(W2, wbuf, FF, Dm);
    gemm_kernel<4><<<dim3(Dm / 128, Sq / 128, 2), 256, 0, stream>>>(
        gb_, wbuf, Sq, Dm, FF, FF / 2, nullptr, out, nullptr);
}

// Round 11
// 464.286 us; speedup vs baseline: 1.0826x; 1.0625x over previous
//
#include <hip/hip_runtime.h>
#include <hip/hip_bf16.h>

#define Sq 2048
#define Dm 2048
#define HDim 3072
#define QKVDim 9216
#define NH 24
#define DH 128
#define FF 8192
#define ATT_SCALE 0.08838834764831845f

using bf16 = __hip_bfloat16;
typedef __attribute__((ext_vector_type(8))) short bf16x8;
typedef __attribute__((ext_vector_type(4))) float f32x4;
typedef unsigned int u32;
typedef unsigned long long u64;
typedef __attribute__((ext_vector_type(4))) u32 u32x4;

// async global->LDS, 16B per lane; LDS dest = wave-uniform base + lane*16
__device__ __forceinline__ void gload_lds16(const void* g, void* l) {
    __builtin_amdgcn_global_load_lds(
        (const __attribute__((address_space(1))) void*)g,
        (__attribute__((address_space(3))) void*)l, 16, 0, 0);
}

// ---------------- LayerNorm + RMSNorm fused ----------------
__global__ __launch_bounds__(256) void ln_rms_kernel(
    const float* __restrict__ x, const float* __restrict__ g, const float* __restrict__ b,
    const float* __restrict__ ag, float* __restrict__ xnf, bf16* __restrict__ h)
{
    __shared__ float redA[4], redB[4], redC[4];
    int row = blockIdx.x;
    int t = threadIdx.x;
    int lane = t & 63, wid = t >> 6;
    const float* xr = x + (size_t)row * Dm;

    float v[8];
    float sum = 0.f, ssq = 0.f;
#pragma unroll
    for (int i = 0; i < 8; i++) {
        float f = xr[t + 256 * i];
        v[i] = f; sum += f; ssq += f * f;
    }
#pragma unroll
    for (int off = 32; off > 0; off >>= 1) {
        sum += __shfl_down(sum, off);
        ssq += __shfl_down(ssq, off);
    }
    if (lane == 0) { redA[wid] = sum; redB[wid] = ssq; }
    __syncthreads();
    sum = redA[0] + redA[1] + redA[2] + redA[3];
    ssq = redB[0] + redB[1] + redB[2] + redB[3];
    float mu = sum * (1.f / Dm);
    float var = ssq * (1.f / Dm) - mu * mu;
    float rstd = rsqrtf(var + 1e-5f);

    float xn[8];
    float s2 = 0.f;
#pragma unroll
    for (int i = 0; i < 8; i++) {
        int col = t + 256 * i;
        float xv = (v[i] - mu) * rstd * g[col] + b[col];
        xn[i] = xv;
        xnf[(size_t)row * Dm + col] = xv;
        s2 += xv * xv;
    }
#pragma unroll
    for (int off = 32; off > 0; off >>= 1) s2 += __shfl_down(s2, off);
    if (lane == 0) redC[wid] = s2;
    __syncthreads();
    s2 = redC[0] + redC[1] + redC[2] + redC[3];
    float rms = rsqrtf(s2 * (1.f / Dm) + 1e-5f);
#pragma unroll
    for (int i = 0; i < 8; i++) {
        int col = t + 256 * i;
        h[(size_t)row * Dm + col] = __float2bfloat16(xn[i] * rms * ag[col]);
    }
}

// ---------------- transpose + fp32->bf16 convert: W[K][N] -> Wt[N][K] ----------------
__global__ __launch_bounds__(256) void transpose_cvt_kernel(
    const float* __restrict__ W, bf16* __restrict__ Wt, int K, int N)
{
    __shared__ float tile[32][36];
    int n0 = blockIdx.x * 32, k0 = blockIdx.y * 32;
    int t = threadIdx.x;
    int r = t >> 3, c4 = (t & 7) * 4;
    f32x4 v = *reinterpret_cast<const f32x4*>(W + (size_t)(k0 + r) * N + n0 + c4);
    *reinterpret_cast<f32x4*>(&tile[r][c4]) = v;
    __syncthreads();
    int nr = t >> 3, kc = (t & 7) * 4;
    bf16 o4[4];
    o4[0] = __float2bfloat16(tile[kc + 0][nr]);
    o4[1] = __float2bfloat16(tile[kc + 1][nr]);
    o4[2] = __float2bfloat16(tile[kc + 2][nr]);
    o4[3] = __float2bfloat16(tile[kc + 3][nr]);
    *reinterpret_cast<u64*>(Wt + (size_t)(n0 + nr) * K + k0 + kc) = *reinterpret_cast<const u64*>(o4);
}

// 3-matrix variant for fused QKV weight transpose (z selects matrix)
__global__ __launch_bounds__(256) void transpose_cvt3_kernel(
    const float* __restrict__ Wa, const float* __restrict__ Wb, const float* __restrict__ Wc,
    bf16* __restrict__ Wt, int K, int N)
{
    __shared__ float tile[32][36];
    const float* W = blockIdx.z == 0 ? Wa : (blockIdx.z == 1 ? Wb : Wc);
    bf16* dst = Wt + (size_t)blockIdx.z * N * K;
    int n0 = blockIdx.x * 32, k0 = blockIdx.y * 32;
    int t = threadIdx.x;
    int r = t >> 3, c4 = (t & 7) * 4;
    f32x4 v = *reinterpret_cast<const f32x4*>(W + (size_t)(k0 + r) * N + n0 + c4);
    *reinterpret_cast<f32x4*>(&tile[r][c4]) = v;
    __syncthreads();
    int nr = t >> 3, kc = (t & 7) * 4;
    bf16 o4[4];
    o4[0] = __float2bfloat16(tile[kc + 0][nr]);
    o4[1] = __float2bfloat16(tile[kc + 1][nr]);
    o4[2] = __float2bfloat16(tile[kc + 2][nr]);
    o4[3] = __float2bfloat16(tile[kc + 3][nr]);
    *reinterpret_cast<u64*>(dst + (size_t)(n0 + nr) * K + k0 + kc) = *reinterpret_cast<const u64*>(o4);
}

// ---------------- fused: hb = bf16(xnf); out = xnf + b2 ----------------
__global__ __launch_bounds__(256) void cvt_prefill_kernel(
    const float* __restrict__ xnf, const float* __restrict__ bias,
    bf16* __restrict__ hb, float* __restrict__ o, int N)
{
    int i = (blockIdx.x * 256 + threadIdx.x) * 8;
    int col = i % N;
    f32x4 a = *reinterpret_cast<const f32x4*>(xnf + i);
    f32x4 b = *reinterpret_cast<const f32x4*>(xnf + i + 4);
    bf16 r[8];
#pragma unroll
    for (int j = 0; j < 4; j++) { r[j] = __float2bfloat16(a[j]); r[4 + j] = __float2bfloat16(b[j]); }
    *reinterpret_cast<u32x4*>(hb + i) = *reinterpret_cast<const u32x4*>(r);
    f32x4 b0 = *reinterpret_cast<const f32x4*>(bias + col);
    f32x4 b1v = *reinterpret_cast<const f32x4*>(bias + col + 4);
    f32x4 o0 = {a[0] + b0[0], a[1] + b0[1], a[2] + b0[2], a[3] + b0[3]};
    f32x4 o1 = {b[0] + b1v[0], b[1] + b1v[1], b[2] + b1v[2], b[3] + b1v[3]};
    *reinterpret_cast<f32x4*>(o + i) = o0;
    *reinterpret_cast<f32x4*>(o + i + 4) = o1;
}

// ---------------- 128x128 bf16 MFMA GEMM (m97 structure, BK=64, swizzled) ------
// EPI 0: Cb = bf16(acc);  EPI 2: Cb = bf16(gelu(acc+bias));  EPI 4: atomicAdd(Cf, acc)
template <int EPI>
__global__ __launch_bounds__(256, 4) void gemm_kernel(
    const bf16* __restrict__ A, const bf16* __restrict__ Bt,
    int M, int N, int K, int Ksplit,
    bf16* Cb, float* Cf, const float* __restrict__ bias)
{
    __shared__ __align__(16) bf16 As[128 * 64];
    __shared__ __align__(16) bf16 Bs[128 * 64];
    int m0 = blockIdx.y * 128, n0 = blockIdx.x * 128;
    int kbeg = blockIdx.z * Ksplit, kend = kbeg + Ksplit;
    int tid = threadIdx.x;
    int lane = tid & 63, w = tid >> 6;
    int wr = w >> 1, wc = w & 1;
    int l15 = lane & 15, lhi = lane >> 4;

    int srow = lane >> 3;
    int scol = ((lane & 7) ^ (lane >> 3)) * 8;

    const f32x4 zero4 = {0.f, 0.f, 0.f, 0.f};
    f32x4 acc[4][4];
#pragma unroll
    for (int m = 0; m < 4; m++)
#pragma unroll
        for (int n = 0; n < 4; n++) acc[m][n] = zero4;

    for (int k0 = kbeg; k0 < kend; k0 += 64) {
        __syncthreads();
#pragma unroll
        for (int c = 0; c < 4; c++) {
            int row = w * 32 + c * 8 + srow;
            gload_lds16(A + (size_t)(m0 + row) * K + k0 + scol,
                        (char*)As + w * 4096 + c * 1024);
            gload_lds16(Bt + (size_t)(n0 + row) * K + k0 + scol,
                        (char*)Bs + w * 4096 + c * 1024);
        }
        __syncthreads();
#pragma unroll
        for (int ks = 0; ks < 2; ks++) {
            bf16x8 af[4], bfr[4];
#pragma unroll
            for (int m = 0; m < 4; m++) {
                int r = wr * 64 + m * 16 + l15;
                af[m] = *reinterpret_cast<const bf16x8*>(
                    &As[r * 64 + (((ks << 2) + lhi) ^ (r & 7)) * 8]);
            }
#pragma unroll
            for (int n = 0; n < 4; n++) {
                int r = wc * 64 + n * 16 + l15;
                bfr[n] = *reinterpret_cast<const bf16x8*>(
                    &Bs[r * 64 + (((ks << 2) + lhi) ^ (r & 7)) * 8]);
            }
#pragma unroll
            for (int m = 0; m < 4; m++)
#pragma unroll
                for (int n = 0; n < 4; n++)
                    acc[m][n] = __builtin_amdgcn_mfma_f32_16x16x32_bf16(af[m], bfr[n], acc[m][n], 0, 0, 0);
        }
    }

#pragma unroll
    for (int m = 0; m < 4; m++) {
        int row = m0 + wr * 64 + m * 16 + lhi * 4;
#pragma unroll
        for (int n = 0; n < 4; n++) {
            int col = n0 + wc * 64 + n * 16 + l15;
#pragma unroll
            for (int j = 0; j < 4; j++) {
                float vv = acc[m][n][j];
                size_t idx = (size_t)(row + j) * N + col;
                if (EPI == 0) {
                    Cb[idx] = __float2bfloat16(vv);
                } else if (EPI == 2) {
                    float o = vv + bias[col];
                    float u = 1.5957691216057308f * (o + 0.044715f * o * o * o); // 2*sqrt(2/pi)
                    Cb[idx] = __float2bfloat16(o / (1.0f + __expf(-u)));
                } else {
                    atomicAdd(&Cf[idx], vv);
                }
            }
        }
    }
}

// ---------------- flash-style causal attention (r8 structure + bank fixes) -----
// 1D grid NH*(Sq/64), work-descending. QBLK=64 (4 waves x 16 q-rows).
// Per kb: K(kb+1) gload_lds + V(kb+1)->regs issued BEFORE compute of kb;
// V ds_write + single vmcnt(0) after the compute barrier.
// V-write lane map kv=lhi*2+(w&1)+(w>>1)*8, d0=l15*8 -> bank 4*(vb^(l15&7))+lhi,
// exact 2-way = free.  Pl padded to 76 (row 152B = 6 banks mod 32) -> P writes
// cover all 32 banks (2-way), P reads get 16 distinct start banks.
__global__ __launch_bounds__(256) void attn_kernel(
    const bf16* __restrict__ qkv, bf16* __restrict__ o)
{
    __shared__ __align__(16) bf16 KsF[2][64 * 128];   // swizzled: slot s of row r = block s^(r&7)
    __shared__ __align__(16) bf16 VtF[2][128 * 72];   // V^T, kv-block XOR swizzle
    __shared__ __align__(16) bf16 Pl[4][16][76];      // padded: 152B row stride
    int rank = blockIdx.x;
    int qb = (Sq / 64 - 1) - rank / NH;    // heaviest first
    int head = rank % NH;
    const bf16* q = qkv + head * DH;
    const bf16* k = qkv + HDim + head * DH;
    const bf16* v = qkv + 2 * HDim + head * DH;
    int tid = threadIdx.x, lane = tid & 63, w = tid >> 6;
    int l15 = lane & 15, lhi = lane >> 4;
    int qrow0 = qb * 64 + w * 16;

    bf16x8 aq[4];
    const bf16* qbase = q + (size_t)(qrow0 + l15) * QKVDim;
#pragma unroll
    for (int kk = 0; kk < 4; kk++)
        aq[kk] = *reinterpret_cast<const bf16x8*>(qbase + kk * 32 + lhi * 8);

    // stage helpers
    int krow_st = w * 16;                         // + c*4 + lhi
    int vkv = lhi * 2 + (w & 1) + (w >> 1) * 8;   // conflict-free V write map
    int vd0 = l15 * 8;
    int vxr = l15 & 7;
    const bf16* vbase = v + (size_t)vkv * QKVDim + vd0;

    const f32x4 zero4 = {0.f, 0.f, 0.f, 0.f};
    f32x4 acc_o[8];
#pragma unroll
    for (int db = 0; db < 8; db++) acc_o[db] = zero4;
    float mrow[4], lrow[4];
#pragma unroll
    for (int r = 0; r < 4; r++) { mrow[r] = -1e30f; lrow[r] = 0.f; }

    // prologue: stage kb=0 into buf 0
    {
#pragma unroll
        for (int c = 0; c < 4; c++) {
            int row = krow_st + c * 4 + lhi;
            int cb = l15 ^ (row & 7);
            gload_lds16(k + (size_t)row * QKVDim + cb * 8,
                        (char*)&KsF[0][0] + w * 4096 + c * 1024);
        }
#pragma unroll
        for (int i = 0; i < 4; i++) {
            int kv = vkv + i * 16;
            bf16x8 vv = *reinterpret_cast<const bf16x8*>(vbase + (size_t)(i * 16) * QKVDim);
            int vb = kv >> 3, kr = kv & 7;
#pragma unroll
            for (int j = 0; j < 8; j++)
                VtF[0][(vd0 + j) * 72 + ((vb ^ vxr) << 3) + kr] = ((const bf16*)&vv)[j];
        }
        asm volatile("s_waitcnt vmcnt(0)" ::: "memory");
        __syncthreads();
    }

    for (int kb = 0; kb <= qb; kb++) {
        int kv0 = kb * 64;
        int p = kb & 1;
        bf16x8 vreg[4];
        bool pref = (kb < qb);
        if (pref) {
            int nv0 = kv0 + 64;
#pragma unroll
            for (int c = 0; c < 4; c++) {
                int row = krow_st + c * 4 + lhi;
                int cb = l15 ^ (row & 7);
                gload_lds16(k + (size_t)(nv0 + row) * QKVDim + cb * 8,
                            (char*)&KsF[p ^ 1][0] + w * 4096 + c * 1024);
            }
#pragma unroll
            for (int i = 0; i < 4; i++)
                vreg[i] = *reinterpret_cast<const bf16x8*>(
                    vbase + (size_t)(nv0 + i * 16) * QKVDim - (size_t)vkv * QKVDim
                    + (size_t)vkv * QKVDim);   // = v + (nv0+vkv+i*16)*QKVDim + vd0
        }
        if (pref) {
            int nv0 = kv0 + 64;
#pragma unroll
            for (int i = 0; i < 4; i++)
                vreg[i] = *reinterpret_cast<const bf16x8*>(
                    v + (size_t)(nv0 + vkv + i * 16) * QKVDim + vd0);
        }

        // ---- compute on buf p ----
        f32x4 sacc[4];
#pragma unroll
        for (int nb = 0; nb < 4; nb++) {
            sacc[nb] = zero4;
            int krow = nb * 16 + l15;
#pragma unroll
            for (int kk = 0; kk < 4; kk++) {
                const char* kp = (const char*)&KsF[p][0] + krow * 256 +
                                 ((kk * 64 + lhi * 16) ^ ((krow & 7) << 4));
                bf16x8 bk = *reinterpret_cast<const bf16x8*>(kp);
                sacc[nb] = __builtin_amdgcn_mfma_f32_16x16x32_bf16(aq[kk], bk, sacc[nb], 0, 0, 0);
            }
        }

        bool diag = (kb == qb);
        float sv[4][4];
        float pm[4];
#pragma unroll
        for (int r = 0; r < 4; r++) pm[r] = -1e30f;
#pragma unroll
        for (int nb = 0; nb < 4; nb++) {
            int kvc = kv0 + nb * 16 + l15;
#pragma unroll
            for (int r = 0; r < 4; r++) {
                int qr = qrow0 + lhi * 4 + r;
                float s = sacc[nb][r] * ATT_SCALE;
                if (diag && kvc > qr) s = -1e30f;
                sv[nb][r] = s;
                pm[r] = fmaxf(pm[r], s);
            }
        }
#pragma unroll
        for (int off = 1; off < 16; off <<= 1)
#pragma unroll
            for (int r = 0; r < 4; r++)
                pm[r] = fmaxf(pm[r], __shfl_xor(pm[r], off));

        float ls[4];
#pragma unroll
        for (int r = 0; r < 4; r++) {
            float mnew = fmaxf(mrow[r], pm[r]);
            float sc = __expf(mrow[r] - mnew);
            mrow[r] = mnew;
            lrow[r] *= sc;
#pragma unroll
            for (int db = 0; db < 8; db++) acc_o[db][r] *= sc;
            float lsr = 0.f;
#pragma unroll
            for (int nb = 0; nb < 4; nb++) {
                float pp = __expf(sv[nb][r] - mnew);
                sv[nb][r] = pp;
                lsr += pp;
            }
            ls[r] = lsr;
        }
#pragma unroll
        for (int off = 1; off < 16; off <<= 1)
#pragma unroll
            for (int r = 0; r < 4; r++)
                ls[r] += __shfl_xor(ls[r], off);
#pragma unroll
        for (int r = 0; r < 4; r++) lrow[r] += ls[r];

#pragma unroll
        for (int nb = 0; nb < 4; nb++)
#pragma unroll
            for (int r = 0; r < 4; r++)
                Pl[w][lhi * 4 + r][nb * 16 + l15] = __float2bfloat16(sv[nb][r]);

#pragma unroll
        for (int ks = 0; ks < 2; ks++) {
            bf16x8 ap = *reinterpret_cast<const bf16x8*>(&Pl[w][l15][ks * 32 + lhi * 8]);
#pragma unroll
            for (int db = 0; db < 8; db++) {
                int dv = db * 16 + l15;
                int blk = (ks * 4 + lhi) ^ ((dv >> 3) & 7);
                bf16x8 bv = *reinterpret_cast<const bf16x8*>(&VtF[p][dv * 72 + blk * 8]);
                acc_o[db] = __builtin_amdgcn_mfma_f32_16x16x32_bf16(ap, bv, acc_o[db], 0, 0, 0);
            }
        }

        __syncthreads();                      // everyone done reading VtF[p]
        if (pref) {
#pragma unroll
            for (int i = 0; i < 4; i++) {
                int kv = vkv + i * 16;
                int vb = kv >> 3, kr = kv & 7;
#pragma unroll
                for (int j = 0; j < 8; j++)
                    VtF[p ^ 1][(vd0 + j) * 72 + ((vb ^ vxr) << 3) + kr] = ((const bf16*)&vreg[i])[j];
            }
            asm volatile("s_waitcnt vmcnt(0)" ::: "memory");
            __syncthreads();                  // buf p^1 (K via DMA, V via ds_write) ready
        }
    }

#pragma unroll
    for (int db = 0; db < 8; db++)
#pragma unroll
        for (int r = 0; r < 4; r++) {
            int qr = qrow0 + lhi * 4 + r;
            float val = acc_o[db][r] / lrow[r];
            o[(size_t)qr * HDim + head * DH + db * 16 + l15] = __float2bfloat16(val);
        }
}

// ---------------- host launch ----------------
extern "C" void kernel_launch(void* const* d_in, const int* in_sizes, int n_in,
                              void* d_out, int out_size, void* d_ws, size_t ws_size,
                              hipStream_t stream)
{
    const float* x     = (const float*)d_in[0];
    const float* ln_g  = (const float*)d_in[1];
    const float* ln_b  = (const float*)d_in[2];
    const float* attng = (const float*)d_in[3];
    const float* Wq    = (const float*)d_in[4];
    const float* Wk    = (const float*)d_in[5];
    const float* Wv    = (const float*)d_in[6];
    const float* Wo    = (const float*)d_in[7];
    const float* W1    = (const float*)d_in[8];
    const float* b1    = (const float*)d_in[9];
    const float* W2    = (const float*)d_in[10];
    const float* b2    = (const float*)d_in[11];
    float* out = (float*)d_out;
    char* ws = (char*)d_ws;

    bf16*  wbuf = (bf16*)(ws + 0);           // 38 MB: transposed weights
    float* xnf  = (float*)(ws + 39845888);   // 16 MB: LN out fp32 -> x2 after Wo accum
    bf16*  hbuf = (bf16*)(ws + 56623104);    //  8 MB: rmsnorm bf16 -> x2 bf16
    bf16*  qkv  = (bf16*)(ws + 65011712);    // 36 MB: fused q|k|v; later FFN hidden
    bf16*  ob_  = (bf16*)(ws + 102760448);   // 12 MB: attention out
    bf16*  gb_  = qkv;

    ln_rms_kernel<<<Sq, 256, 0, stream>>>(x, ln_g, ln_b, attng, xnf, hbuf);

    transpose_cvt3_kernel<<<dim3(HDim / 32, Dm / 32, 3), 256, 0, stream>>>(
        Wq, Wk, Wv, wbuf, Dm, HDim);
    gemm_kernel<0><<<dim3(QKVDim / 128, Sq / 128, 1), 256, 0, stream>>>(
        hbuf, wbuf, Sq, QKVDim, Dm, Dm, qkv, nullptr, nullptr);

    attn_kernel<<<dim3(NH * Sq / 64), 256, 0, stream>>>(qkv, ob_);

    transpose_cvt_kernel<<<dim3(Dm / 32, HDim / 32), 256, 0, stream>>>(Wo, wbuf, HDim, Dm);
    gemm_kernel<4><<<dim3(Dm / 128, Sq / 128, 2), 256, 0, stream>>>(
        ob_, wbuf, Sq, Dm, HDim, HDim / 2, nullptr, xnf, nullptr);
    cvt_prefill_kernel<<<(Sq * Dm) / (256 * 8), 256, 0, stream>>>(xnf, b2, hbuf, out, Dm);

    transpose_cvt_kernel<<<dim3(FF / 32, Dm / 32), 256, 0, stream>>>(W1, wbuf, Dm, FF);
    gemm_kernel<2><<<dim3(FF / 128, Sq / 128, 1), 256, 0, stream>>>(
        hbuf, wbuf, Sq, FF, Dm, Dm, gb_, nullptr, b1);

    transpose_cvt_kernel<<<dim3(Dm / 32, FF / 32), 256, 0, stream>>>(W2, wbuf, FF, Dm);
    gemm_kernel<4><<<dim3(Dm / 128, Sq / 128, 2), 256, 0, stream>>>(
        gb_, wbuf, Sq, Dm, FF, FF / 2, nullptr, out, nullptr);
}

// Round 12
// 461.911 us; speedup vs baseline: 1.0881x; 1.0051x over previous
//
#include <hip/hip_runtime.h>
#include <hip/hip_bf16.h>

#define Sq 2048
#define Dm 2048
#define HDim 3072
#define QKVDim 9216
#define NH 24
#define DH 128
#define FF 8192
#define ATT_SCALE 0.08838834764831845f

using bf16 = __hip_bfloat16;
typedef __attribute__((ext_vector_type(8))) short bf16x8;
typedef __attribute__((ext_vector_type(4))) float f32x4;
typedef unsigned int u32;
typedef unsigned long long u64;
typedef __attribute__((ext_vector_type(4))) u32 u32x4;

// async global->LDS, 16B per lane; LDS dest = wave-uniform base + lane*16
__device__ __forceinline__ void gload_lds16(const void* g, void* l) {
    __builtin_amdgcn_global_load_lds(
        (const __attribute__((address_space(1))) void*)g,
        (__attribute__((address_space(3))) void*)l, 16, 0, 0);
}

// ---------------- LayerNorm + RMSNorm fused ----------------
__global__ __launch_bounds__(256) void ln_rms_kernel(
    const float* __restrict__ x, const float* __restrict__ g, const float* __restrict__ b,
    const float* __restrict__ ag, float* __restrict__ xnf, bf16* __restrict__ h)
{
    __shared__ float redA[4], redB[4], redC[4];
    int row = blockIdx.x;
    int t = threadIdx.x;
    int lane = t & 63, wid = t >> 6;
    const float* xr = x + (size_t)row * Dm;

    float v[8];
    float sum = 0.f, ssq = 0.f;
#pragma unroll
    for (int i = 0; i < 8; i++) {
        float f = xr[t + 256 * i];
        v[i] = f; sum += f; ssq += f * f;
    }
#pragma unroll
    for (int off = 32; off > 0; off >>= 1) {
        sum += __shfl_down(sum, off);
        ssq += __shfl_down(ssq, off);
    }
    if (lane == 0) { redA[wid] = sum; redB[wid] = ssq; }
    __syncthreads();
    sum = redA[0] + redA[1] + redA[2] + redA[3];
    ssq = redB[0] + redB[1] + redB[2] + redB[3];
    float mu = sum * (1.f / Dm);
    float var = ssq * (1.f / Dm) - mu * mu;
    float rstd = rsqrtf(var + 1e-5f);

    float xn[8];
    float s2 = 0.f;
#pragma unroll
    for (int i = 0; i < 8; i++) {
        int col = t + 256 * i;
        float xv = (v[i] - mu) * rstd * g[col] + b[col];
        xn[i] = xv;
        xnf[(size_t)row * Dm + col] = xv;
        s2 += xv * xv;
    }
#pragma unroll
    for (int off = 32; off > 0; off >>= 1) s2 += __shfl_down(s2, off);
    if (lane == 0) redC[wid] = s2;
    __syncthreads();
    s2 = redC[0] + redC[1] + redC[2] + redC[3];
    float rms = rsqrtf(s2 * (1.f / Dm) + 1e-5f);
#pragma unroll
    for (int i = 0; i < 8; i++) {
        int col = t + 256 * i;
        h[(size_t)row * Dm + col] = __float2bfloat16(xn[i] * rms * ag[col]);
    }
}

// ---------------- transpose + fp32->bf16 convert: W[K][N] -> Wt[N][K] ----------------
__global__ __launch_bounds__(256) void transpose_cvt_kernel(
    const float* __restrict__ W, bf16* __restrict__ Wt, int K, int N)
{
    __shared__ float tile[32][36];
    int n0 = blockIdx.x * 32, k0 = blockIdx.y * 32;
    int t = threadIdx.x;
    int r = t >> 3, c4 = (t & 7) * 4;
    f32x4 v = *reinterpret_cast<const f32x4*>(W + (size_t)(k0 + r) * N + n0 + c4);
    *reinterpret_cast<f32x4*>(&tile[r][c4]) = v;
    __syncthreads();
    int nr = t >> 3, kc = (t & 7) * 4;
    bf16 o4[4];
    o4[0] = __float2bfloat16(tile[kc + 0][nr]);
    o4[1] = __float2bfloat16(tile[kc + 1][nr]);
    o4[2] = __float2bfloat16(tile[kc + 2][nr]);
    o4[3] = __float2bfloat16(tile[kc + 3][nr]);
    *reinterpret_cast<u64*>(Wt + (size_t)(n0 + nr) * K + k0 + kc) = *reinterpret_cast<const u64*>(o4);
}

// 3-matrix variant for fused QKV weight transpose (z selects matrix)
__global__ __launch_bounds__(256) void transpose_cvt3_kernel(
    const float* __restrict__ Wa, const float* __restrict__ Wb, const float* __restrict__ Wc,
    bf16* __restrict__ Wt, int K, int N)
{
    __shared__ float tile[32][36];
    const float* W = blockIdx.z == 0 ? Wa : (blockIdx.z == 1 ? Wb : Wc);
    bf16* dst = Wt + (size_t)blockIdx.z * N * K;
    int n0 = blockIdx.x * 32, k0 = blockIdx.y * 32;
    int t = threadIdx.x;
    int r = t >> 3, c4 = (t & 7) * 4;
    f32x4 v = *reinterpret_cast<const f32x4*>(W + (size_t)(k0 + r) * N + n0 + c4);
    *reinterpret_cast<f32x4*>(&tile[r][c4]) = v;
    __syncthreads();
    int nr = t >> 3, kc = (t & 7) * 4;
    bf16 o4[4];
    o4[0] = __float2bfloat16(tile[kc + 0][nr]);
    o4[1] = __float2bfloat16(tile[kc + 1][nr]);
    o4[2] = __float2bfloat16(tile[kc + 2][nr]);
    o4[3] = __float2bfloat16(tile[kc + 3][nr]);
    *reinterpret_cast<u64*>(dst + (size_t)(n0 + nr) * K + k0 + kc) = *reinterpret_cast<const u64*>(o4);
}

// ---------------- fused: hb = bf16(xnf); out = xnf + b2 ----------------
__global__ __launch_bounds__(256) void cvt_prefill_kernel(
    const float* __restrict__ xnf, const float* __restrict__ bias,
    bf16* __restrict__ hb, float* __restrict__ o, int N)
{
    int i = (blockIdx.x * 256 + threadIdx.x) * 8;
    int col = i % N;
    f32x4 a = *reinterpret_cast<const f32x4*>(xnf + i);
    f32x4 b = *reinterpret_cast<const f32x4*>(xnf + i + 4);
    bf16 r[8];
#pragma unroll
    for (int j = 0; j < 4; j++) { r[j] = __float2bfloat16(a[j]); r[4 + j] = __float2bfloat16(b[j]); }
    *reinterpret_cast<u32x4*>(hb + i) = *reinterpret_cast<const u32x4*>(r);
    f32x4 b0 = *reinterpret_cast<const f32x4*>(bias + col);
    f32x4 b1v = *reinterpret_cast<const f32x4*>(bias + col + 4);
    f32x4 o0 = {a[0] + b0[0], a[1] + b0[1], a[2] + b0[2], a[3] + b0[3]};
    f32x4 o1 = {b[0] + b1v[0], b[1] + b1v[1], b[2] + b1v[2], b[3] + b1v[3]};
    *reinterpret_cast<f32x4*>(o + i) = o0;
    *reinterpret_cast<f32x4*>(o + i + 4) = o1;
}

// ---------------- 128x128 bf16 MFMA GEMM (m97 structure, BK=64, swizzled) ------
// EPI 0: Cb = bf16(acc);  EPI 2: Cb = bf16(gelu(acc+bias));  EPI 4: atomicAdd(Cf, acc)
template <int EPI>
__global__ __launch_bounds__(256, 4) void gemm_kernel(
    const bf16* __restrict__ A, const bf16* __restrict__ Bt,
    int M, int N, int K, int Ksplit,
    bf16* Cb, float* Cf, const float* __restrict__ bias)
{
    __shared__ __align__(16) bf16 As[128 * 64];
    __shared__ __align__(16) bf16 Bs[128 * 64];
    int m0 = blockIdx.y * 128, n0 = blockIdx.x * 128;
    int kbeg = blockIdx.z * Ksplit, kend = kbeg + Ksplit;
    int tid = threadIdx.x;
    int lane = tid & 63, w = tid >> 6;
    int wr = w >> 1, wc = w & 1;
    int l15 = lane & 15, lhi = lane >> 4;

    int srow = lane >> 3;
    int scol = ((lane & 7) ^ (lane >> 3)) * 8;

    const f32x4 zero4 = {0.f, 0.f, 0.f, 0.f};
    f32x4 acc[4][4];
#pragma unroll
    for (int m = 0; m < 4; m++)
#pragma unroll
        for (int n = 0; n < 4; n++) acc[m][n] = zero4;

    for (int k0 = kbeg; k0 < kend; k0 += 64) {
        __syncthreads();
#pragma unroll
        for (int c = 0; c < 4; c++) {
            int row = w * 32 + c * 8 + srow;
            gload_lds16(A + (size_t)(m0 + row) * K + k0 + scol,
                        (char*)As + w * 4096 + c * 1024);
            gload_lds16(Bt + (size_t)(n0 + row) * K + k0 + scol,
                        (char*)Bs + w * 4096 + c * 1024);
        }
        __syncthreads();
#pragma unroll
        for (int ks = 0; ks < 2; ks++) {
            bf16x8 af[4], bfr[4];
#pragma unroll
            for (int m = 0; m < 4; m++) {
                int r = wr * 64 + m * 16 + l15;
                af[m] = *reinterpret_cast<const bf16x8*>(
                    &As[r * 64 + (((ks << 2) + lhi) ^ (r & 7)) * 8]);
            }
#pragma unroll
            for (int n = 0; n < 4; n++) {
                int r = wc * 64 + n * 16 + l15;
                bfr[n] = *reinterpret_cast<const bf16x8*>(
                    &Bs[r * 64 + (((ks << 2) + lhi) ^ (r & 7)) * 8]);
            }
#pragma unroll
            for (int m = 0; m < 4; m++)
#pragma unroll
                for (int n = 0; n < 4; n++)
                    acc[m][n] = __builtin_amdgcn_mfma_f32_16x16x32_bf16(af[m], bfr[n], acc[m][n], 0, 0, 0);
        }
    }

#pragma unroll
    for (int m = 0; m < 4; m++) {
        int row = m0 + wr * 64 + m * 16 + lhi * 4;
#pragma unroll
        for (int n = 0; n < 4; n++) {
            int col = n0 + wc * 64 + n * 16 + l15;
#pragma unroll
            for (int j = 0; j < 4; j++) {
                float vv = acc[m][n][j];
                size_t idx = (size_t)(row + j) * N + col;
                if (EPI == 0) {
                    Cb[idx] = __float2bfloat16(vv);
                } else if (EPI == 2) {
                    float o = vv + bias[col];
                    float u = 1.5957691216057308f * (o + 0.044715f * o * o * o); // 2*sqrt(2/pi)
                    Cb[idx] = __float2bfloat16(o / (1.0f + __expf(-u)));
                } else {
                    atomicAdd(&Cf[idx], vv);
                }
            }
        }
    }
}

// ---------------- flash-style causal attention ----------------
// r11 structure + (1) l-sum via MFMA ones-operand (no sum shfl tree, no lrow),
// (2) defer-max rescale (THR=8), (3) single barrier per KV tile.
// Per kb: K(kb+1) gload_lds + V(kb+1)->regs issued BEFORE compute of kb;
// V ds_write late (after PV, before the barrier). __syncthreads() drains
// vmcnt/lgkm, so staged K and V-writes are visible after it.
__global__ __launch_bounds__(256) void attn_kernel(
    const bf16* __restrict__ qkv, bf16* __restrict__ o)
{
    __shared__ __align__(16) bf16 KsF[2][64 * 128];   // swizzled: slot s of row r = block s^(r&7)
    __shared__ __align__(16) bf16 VtF[2][128 * 72];   // V^T, kv-block XOR swizzle
    __shared__ __align__(16) bf16 Pl[4][16][76];      // padded: 152B row stride
    int rank = blockIdx.x;
    int qb = (Sq / 64 - 1) - rank / NH;    // heaviest first
    int head = rank % NH;
    const bf16* q = qkv + head * DH;
    const bf16* k = qkv + HDim + head * DH;
    const bf16* v = qkv + 2 * HDim + head * DH;
    int tid = threadIdx.x, lane = tid & 63, w = tid >> 6;
    int l15 = lane & 15, lhi = lane >> 4;
    int qrow0 = qb * 64 + w * 16;

    bf16x8 aq[4];
    const bf16* qbase = q + (size_t)(qrow0 + l15) * QKVDim;
#pragma unroll
    for (int kk = 0; kk < 4; kk++)
        aq[kk] = *reinterpret_cast<const bf16x8*>(qbase + kk * 32 + lhi * 8);

    // bf16 ones fragment for the l-sum MFMA
    bf16x8 vones;
#pragma unroll
    for (int j = 0; j < 8; j++) vones[j] = (short)0x3F80;

    // stage helpers
    int krow_st = w * 16;                         // + c*4 + lhi
    int vkv = lhi * 2 + (w & 1) + (w >> 1) * 8;   // V write lane map
    int vd0 = l15 * 8;
    int vxr = l15 & 7;
    const bf16* vbase = v + (size_t)vkv * QKVDim + vd0;

    const f32x4 zero4 = {0.f, 0.f, 0.f, 0.f};
    f32x4 acc_o[8];
#pragma unroll
    for (int db = 0; db < 8; db++) acc_o[db] = zero4;
    f32x4 acc_l = zero4;
    float mrow[4];
#pragma unroll
    for (int r = 0; r < 4; r++) mrow[r] = -1e30f;

    // prologue: stage kb=0 into buf 0
    {
#pragma unroll
        for (int c = 0; c < 4; c++) {
            int row = krow_st + c * 4 + lhi;
            int cb = l15 ^ (row & 7);
            gload_lds16(k + (size_t)row * QKVDim + cb * 8,
                        (char*)&KsF[0][0] + w * 4096 + c * 1024);
        }
#pragma unroll
        for (int i = 0; i < 4; i++) {
            int kv = vkv + i * 16;
            bf16x8 vv = *reinterpret_cast<const bf16x8*>(vbase + (size_t)(i * 16) * QKVDim);
            int vb = kv >> 3, kr = kv & 7;
#pragma unroll
            for (int j = 0; j < 8; j++)
                VtF[0][(vd0 + j) * 72 + ((vb ^ vxr) << 3) + kr] = ((const bf16*)&vv)[j];
        }
        __syncthreads();   // drains vmcnt+lgkm: K(0), V(0) visible
    }

    for (int kb = 0; kb <= qb; kb++) {
        int kv0 = kb * 64;
        int p = kb & 1;
        bf16x8 vreg[4];
        bool pref = (kb < qb);
        if (pref) {
            int nv0 = kv0 + 64;
#pragma unroll
            for (int c = 0; c < 4; c++) {
                int row = krow_st + c * 4 + lhi;
                int cb = l15 ^ (row & 7);
                gload_lds16(k + (size_t)(nv0 + row) * QKVDim + cb * 8,
                            (char*)&KsF[p ^ 1][0] + w * 4096 + c * 1024);
            }
#pragma unroll
            for (int i = 0; i < 4; i++)
                vreg[i] = *reinterpret_cast<const bf16x8*>(
                    vbase + (size_t)(nv0 + i * 16) * QKVDim);
        }

        // ---- QK^T on buf p ----
        f32x4 sacc[4];
#pragma unroll
        for (int nb = 0; nb < 4; nb++) {
            sacc[nb] = zero4;
            int krow = nb * 16 + l15;
#pragma unroll
            for (int kk = 0; kk < 4; kk++) {
                const char* kp = (const char*)&KsF[p][0] + krow * 256 +
                                 ((kk * 64 + lhi * 16) ^ ((krow & 7) << 4));
                bf16x8 bk = *reinterpret_cast<const bf16x8*>(kp);
                sacc[nb] = __builtin_amdgcn_mfma_f32_16x16x32_bf16(aq[kk], bk, sacc[nb], 0, 0, 0);
            }
        }

        bool diag = (kb == qb);
        float sv[4][4];
        float pm[4];
#pragma unroll
        for (int r = 0; r < 4; r++) pm[r] = -1e30f;
#pragma unroll
        for (int nb = 0; nb < 4; nb++) {
            int kvc = kv0 + nb * 16 + l15;
#pragma unroll
            for (int r = 0; r < 4; r++) {
                int qr = qrow0 + lhi * 4 + r;
                float s = sacc[nb][r] * ATT_SCALE;
                if (diag && kvc > qr) s = -1e30f;
                sv[nb][r] = s;
                pm[r] = fmaxf(pm[r], s);
            }
        }
#pragma unroll
        for (int off = 1; off < 16; off <<= 1)
#pragma unroll
            for (int r = 0; r < 4; r++)
                pm[r] = fmaxf(pm[r], __shfl_xor(pm[r], off));

        // defer-max: only rescale when the max grew by more than THR=8
        float nm[4];
        bool need = false;
#pragma unroll
        for (int r = 0; r < 4; r++) {
            nm[r] = fmaxf(mrow[r], pm[r]);
            need = need || (pm[r] > mrow[r] + 8.f);
        }
        if (__any(need)) {
#pragma unroll
            for (int r = 0; r < 4; r++) {
                float sc = __expf(mrow[r] - nm[r]);
                mrow[r] = nm[r];
                acc_l[r] *= sc;
#pragma unroll
                for (int db = 0; db < 8; db++) acc_o[db][r] *= sc;
            }
        }

#pragma unroll
        for (int nb = 0; nb < 4; nb++)
#pragma unroll
            for (int r = 0; r < 4; r++)
                sv[nb][r] = __expf(sv[nb][r] - mrow[r]);

        // P -> LDS (per-wave tile)
#pragma unroll
        for (int nb = 0; nb < 4; nb++)
#pragma unroll
            for (int r = 0; r < 4; r++)
                Pl[w][lhi * 4 + r][nb * 16 + l15] = __float2bfloat16(sv[nb][r]);

        // O += P V ; l += P * ones
#pragma unroll
        for (int ks = 0; ks < 2; ks++) {
            bf16x8 ap = *reinterpret_cast<const bf16x8*>(&Pl[w][l15][ks * 32 + lhi * 8]);
            acc_l = __builtin_amdgcn_mfma_f32_16x16x32_bf16(ap, vones, acc_l, 0, 0, 0);
#pragma unroll
            for (int db = 0; db < 8; db++) {
                int dv = db * 16 + l15;
                int blk = (ks * 4 + lhi) ^ ((dv >> 3) & 7);
                bf16x8 bv = *reinterpret_cast<const bf16x8*>(&VtF[p][dv * 72 + blk * 8]);
                acc_o[db] = __builtin_amdgcn_mfma_f32_16x16x32_bf16(ap, bv, acc_o[db], 0, 0, 0);
            }
        }

        // V(kb+1) write late (targets buf p^1, disjoint from this tile's reads)
        if (pref) {
#pragma unroll
            for (int i = 0; i < 4; i++) {
                int kv = vkv + i * 16;
                int vb = kv >> 3, kr = kv & 7;
#pragma unroll
                for (int j = 0; j < 8; j++)
                    VtF[p ^ 1][(vd0 + j) * 72 + ((vb ^ vxr) << 3) + kr] = ((const bf16*)&vreg[i])[j];
            }
        }
        __syncthreads();   // single barrier: drains K-DMA + V-writes; orders buf reuse
    }

#pragma unroll
    for (int db = 0; db < 8; db++)
#pragma unroll
        for (int r = 0; r < 4; r++) {
            int qr = qrow0 + lhi * 4 + r;
            float val = acc_o[db][r] / acc_l[r];
            o[(size_t)qr * HDim + head * DH + db * 16 + l15] = __float2bfloat16(val);
        }
}

// ---------------- host launch ----------------
extern "C" void kernel_launch(void* const* d_in, const int* in_sizes, int n_in,
                              void* d_out, int out_size, void* d_ws, size_t ws_size,
                              hipStream_t stream)
{
    const float* x     = (const float*)d_in[0];
    const float* ln_g  = (const float*)d_in[1];
    const float* ln_b  = (const float*)d_in[2];
    const float* attng = (const float*)d_in[3];
    const float* Wq    = (const float*)d_in[4];
    const float* Wk    = (const float*)d_in[5];
    const float* Wv    = (const float*)d_in[6];
    const float* Wo    = (const float*)d_in[7];
    const float* W1    = (const float*)d_in[8];
    const float* b1    = (const float*)d_in[9];
    const float* W2    = (const float*)d_in[10];
    const float* b2    = (const float*)d_in[11];
    float* out = (float*)d_out;
    char* ws = (char*)d_ws;

    bf16*  wbuf = (bf16*)(ws + 0);           // 38 MB: transposed weights
    float* xnf  = (float*)(ws + 39845888);   // 16 MB: LN out fp32 -> x2 after Wo accum
    bf16*  hbuf = (bf16*)(ws + 56623104);    //  8 MB: rmsnorm bf16 -> x2 bf16
    bf16*  qkv  = (bf16*)(ws + 65011712);    // 36 MB: fused q|k|v; later FFN hidden
    bf16*  ob_  = (bf16*)(ws + 102760448);   // 12 MB: attention out
    bf16*  gb_  = qkv;

    ln_rms_kernel<<<Sq, 256, 0, stream>>>(x, ln_g, ln_b, attng, xnf, hbuf);

    transpose_cvt3_kernel<<<dim3(HDim / 32, Dm / 32, 3), 256, 0, stream>>>(
        Wq, Wk, Wv, wbuf, Dm, HDim);
    gemm_kernel<0><<<dim3(QKVDim / 128, Sq / 128, 1), 256, 0, stream>>>(
        hbuf, wbuf, Sq, QKVDim, Dm, Dm, qkv, nullptr, nullptr);

    attn_kernel<<<dim3(NH * Sq / 64), 256, 0, stream>>>(qkv, ob_);

    transpose_cvt_kernel<<<dim3(Dm / 32, HDim / 32), 256, 0, stream>>>(Wo, wbuf, HDim, Dm);
    gemm_kernel<4><<<dim3(Dm / 128, Sq / 128, 2), 256, 0, stream>>>(
        ob_, wbuf, Sq, Dm, HDim, HDim / 2, nullptr, xnf, nullptr);
    cvt_prefill_kernel<<<(Sq * Dm) / (256 * 8), 256, 0, stream>>>(xnf, b2, hbuf, out, Dm);

    transpose_cvt_kernel<<<dim3(FF / 32, Dm / 32), 256, 0, stream>>>(W1, wbuf, Dm, FF);
    gemm_kernel<2><<<dim3(FF / 128, Sq / 128, 1), 256, 0, stream>>>(
        hbuf, wbuf, Sq, FF, Dm, Dm, gb_, nullptr, b1);

    transpose_cvt_kernel<<<dim3(Dm / 32, FF / 32), 256, 0, stream>>>(W2, wbuf, FF, Dm);
    gemm_kernel<4><<<dim3(Dm / 128, Sq / 128, 2), 256, 0, stream>>>(
        gb_, wbuf, Sq, Dm, FF, FF / 2, nullptr, out, nullptr);
}